// Round 10
// baseline (1177.920 us; speedup 1.0000x reference)
//
#include <hip/hip_runtime.h>

typedef unsigned short u16;
typedef unsigned int u32;
typedef unsigned long long u64;
typedef short s16x8 __attribute__((ext_vector_type(8)));
typedef float f32x4 __attribute__((ext_vector_type(4)));
typedef u32 u32x4 __attribute__((ext_vector_type(4)));

#define T_SEQ 40
#define EMB 300
#define KPAD 320
#define NCOL 3072  // 3H * 2 dirs

__device__ __forceinline__ u16 f2bf(float x) {
  u32 u = __builtin_bit_cast(u32, x);
  u32 r = (u + 0x7fffu + ((u >> 16) & 1u)) >> 16;  // RNE
  return (u16)r;
}
__device__ __forceinline__ float bf2f(u16 h) {
  return __builtin_bit_cast(float, ((u32)h) << 16);
}
#define LOG2E 1.4426950408889634f
__device__ __forceinline__ float sigm(float x) {
  return 1.0f / (1.0f + __builtin_amdgcn_exp2f(-x * LOG2E));
}
__device__ __forceinline__ float fast_tanh(float x) {
  return 1.0f - 2.0f / (1.0f + __builtin_amdgcn_exp2f(2.0f * LOG2E * x));
}

// ---- init: zero flags/claim (AGENT -> L3, replay-safe), build per-row mask bitmaps
__global__ void k_init(const int* __restrict__ idxs, u64* __restrict__ mask,
                       int* __restrict__ bar) {
  int i = blockIdx.x * 256 + threadIdx.x;
  if (i < 272) __hip_atomic_store(&bar[i], 0, __ATOMIC_RELAXED, __HIP_MEMORY_SCOPE_AGENT);
  if (i < 512) {
    u64 b = 0;
    for (int t = 0; t < T_SEQ; ++t)
      if (idxs[i * T_SEQ + t] != 0) b |= (1ull << t);
    mask[i] = b;
  }
}

// ---- emb f32 [V][300] -> bf16 [V][320] (zero-padded), done once
__global__ void k_prep_emb(const float* __restrict__ emb, u16* __restrict__ emb16) {
  for (int idx = blockIdx.x * 256 + threadIdx.x; idx < 50000 * 160; idx += 4096 * 256) {
    int row = idx / 160, c2 = idx - row * 160;
    int c0 = 2 * c2;
    float v0 = (c0 < EMB) ? emb[(size_t)row * EMB + c0] : 0.0f;
    float v1 = (c0 + 1 < EMB) ? emb[(size_t)row * EMB + c0 + 1] : 0.0f;
    ((u32*)emb16)[(size_t)row * 160 + c2] = (u32)f2bf(v0) | ((u32)f2bf(v1) << 16);
  }
}

// ---- pack w_ih (both dirs) to bf16, K padded 300 -> 320
__global__ void k_prep_wih(const float* __restrict__ wf, const float* __restrict__ wb,
                           u16* __restrict__ wih) {
  int n = blockIdx.x, e = threadIdx.x;
  int dir = (n >= 1536);
  int g = n - dir * 1536;
  const float* src = dir ? wb : wf;
  float v = (e < EMB) ? src[(size_t)g * EMB + e] : 0.0f;
  wih[(size_t)n * KPAD + e] = f2bf(v);
}

// ---- w_hh (both dirs) -> single bf16 (RNE)
__global__ void k_prep_whh(const float* __restrict__ wf, const float* __restrict__ wb,
                           u16* __restrict__ w16) {
  int n = blockIdx.x, k = threadIdx.x;
  int dir = (n >= 1536);
  int g = n - dir * 1536;
  float v = (dir ? wb : wf)[(size_t)g * 512 + k];
  w16[(size_t)n * 512 + k] = f2bf(v);
}

__global__ void k_prep_bias(const float* __restrict__ bihf, const float* __restrict__ bihb,
                            const float* __restrict__ bhhf, const float* __restrict__ bhhb,
                            float* __restrict__ bias_ih, float* __restrict__ bias_hh) {
  int i = blockIdx.x * 1024 + threadIdx.x;
  if (i >= 3072) return;
  int dir = (i >= 1536);
  int g = i - dir * 1536;
  bias_ih[i] = dir ? bihb[g] : bihf[g];
  bias_hh[i] = dir ? bhhb[g] : bhhf[g];
}

// ---- phase A: gi[tok][n] = emb16[idx[tok]] . wih[n] + b_ih[n], output bf16 (nt stores).
__global__ __launch_bounds__(256) void k_gi_gemm(
    const int* __restrict__ idxs, const float* __restrict__ emb,
    const u16* __restrict__ emb16, int use_emb16,
    const u16* __restrict__ wih, const float* __restrict__ bias_ih,
    u16* __restrict__ gi) {
  __shared__ __align__(16) char smem[34816];
  u16(*As)[40] = (u16(*)[40])smem;            // 10240 B
  u16(*Bs)[40] = (u16(*)[40])(smem + 10240);  // 10240 B
  u16(*Cs)[136] = (u16(*)[136])smem;          // 34816 B (reused after K loop)

  const int m0 = blockIdx.x * 128;
  const int n0 = blockIdx.y * 128;
  const int t = threadIdx.x;
  const int w = t >> 6, l = t & 63;
  const int wm = (w >> 1) * 64, wn = (w & 1) * 64;
  const int lr = l & 15, lg = l >> 4;

  f32x4 acc[4][4];
#pragma unroll
  for (int i = 0; i < 4; ++i)
#pragma unroll
    for (int j = 0; j < 4; ++j) acc[i][j] = (f32x4)0.0f;

  const int arow = t >> 1, aseg = t & 1;
  const int tok = idxs[m0 + arow];
  const float* aerow = emb + (size_t)tok * EMB;
  const u16* aerow16 = emb16 + (size_t)tok * KPAD;
  const u16* brow_p = wih + (size_t)(n0 + arow) * KPAD;

  for (int kc = 0; kc < 10; ++kc) {
    const int k0 = kc * 32;
    if (use_emb16) {
      *(uint4*)&As[arow][aseg * 16] = *(const uint4*)(aerow16 + k0 + aseg * 16);
      *(uint4*)(&As[arow][aseg * 16] + 8) = *(const uint4*)(aerow16 + k0 + aseg * 16 + 8);
    } else {
      int cb = k0 + aseg * 16;
      u16* d = &As[arow][aseg * 16];
      if (cb + 15 < EMB) {
        const float4* s = (const float4*)(aerow + cb);
        float4 v0 = s[0], v1 = s[1], v2 = s[2], v3 = s[3];
        uint4 w0, w1;
        w0.x = (u32)f2bf(v0.x) | ((u32)f2bf(v0.y) << 16);
        w0.y = (u32)f2bf(v0.z) | ((u32)f2bf(v0.w) << 16);
        w0.z = (u32)f2bf(v1.x) | ((u32)f2bf(v1.y) << 16);
        w0.w = (u32)f2bf(v1.z) | ((u32)f2bf(v1.w) << 16);
        w1.x = (u32)f2bf(v2.x) | ((u32)f2bf(v2.y) << 16);
        w1.y = (u32)f2bf(v2.z) | ((u32)f2bf(v2.w) << 16);
        w1.z = (u32)f2bf(v3.x) | ((u32)f2bf(v3.y) << 16);
        w1.w = (u32)f2bf(v3.z) | ((u32)f2bf(v3.w) << 16);
        *(uint4*)d = w0;
        *(uint4*)(d + 8) = w1;
      } else {
#pragma unroll
        for (int e = 0; e < 16; ++e) {
          int c = cb + e;
          d[e] = (c < EMB) ? f2bf(aerow[c]) : (u16)0;
        }
      }
    }
    {
      const u16* s = brow_p + k0 + aseg * 16;
      u16* d = &Bs[arow][aseg * 16];
      *(uint4*)d = *(const uint4*)s;
      *(uint4*)(d + 8) = *(const uint4*)(s + 8);
    }
    __syncthreads();
    s16x8 av[4], bv[4];
#pragma unroll
    for (int i = 0; i < 4; ++i) av[i] = *(const s16x8*)&As[wm + i * 16 + lr][lg * 8];
#pragma unroll
    for (int j = 0; j < 4; ++j) bv[j] = *(const s16x8*)&Bs[wn + j * 16 + lr][lg * 8];
#pragma unroll
    for (int i = 0; i < 4; ++i)
#pragma unroll
      for (int j = 0; j < 4; ++j)
        acc[i][j] = __builtin_amdgcn_mfma_f32_16x16x32_bf16(av[i], bv[j], acc[i][j], 0, 0, 0);
    __syncthreads();
  }

  float bj[4];
#pragma unroll
  for (int j = 0; j < 4; ++j) bj[j] = bias_ih[n0 + wn + j * 16 + lr];
#pragma unroll
  for (int i = 0; i < 4; ++i)
#pragma unroll
    for (int j = 0; j < 4; ++j)
#pragma unroll
      for (int r = 0; r < 4; ++r)
        Cs[wm + i * 16 + lg * 4 + r][wn + j * 16 + lr] = f2bf(acc[i][j][r] + bj[j]);
  __syncthreads();
#pragma unroll
  for (int rr = t >> 4; rr < 128; rr += 16) {
    const int cseg = (t & 15) * 8;
    __builtin_nontemporal_store(*(const u32x4*)&Cs[rr][cseg],
                                (u32x4*)(gi + (size_t)(m0 + rr) * NCOL + n0 + cseg));
  }
}

// ---- phase B: persistent bidirectional GRU, one XCD = one group of 16 worker blocks.
// 256 blocks launched, 1/CU via 96KB LDS; first 16 claimants per XCD work (xcd ->
// (m-tile 128, dir), slot -> j 32-slice), rest exit. Wave tile 16m x 32j (8 waves)
// -> each h row read ONCE from L2. Flags: AGENT-scope atomics in L3 (R8's proven
// scheme, k_init-zeroed, replay-safe). Waiting waves run a v_fmac burn chain between
// polls to hold DVFS clocks up. gi prefetched before the poll; h K-loop 2-deep
// pipelined; masked-max/hprev bookkeeping deferred past the publish.
__global__ __launch_bounds__(512) void k_gru_persist(
    const u16* __restrict__ whh16, const float* __restrict__ bias_hh,
    const u16* __restrict__ gi, const u64* __restrict__ mask, u32* __restrict__ hpk,
    float* __restrict__ ymax, int* __restrict__ bar) {
  extern __shared__ u16 wlds[];  // [64 kcg][96 col][8] u16 = 96 KB
  __shared__ int s_claim[2];
  __shared__ int s_arrive;
  const int t = threadIdx.x;
  if (t == 0) {
    int xcd;
    asm volatile("s_getreg_b32 %0, hwreg(HW_REG_XCC_ID)" : "=s"(xcd));
    xcd &= 7;
    int slot =
        __hip_atomic_fetch_add(&bar[256 + xcd], 1, __ATOMIC_RELAXED, __HIP_MEMORY_SCOPE_AGENT);
    s_claim[0] = xcd;
    s_claim[1] = slot;
    s_arrive = 0;
  }
  __syncthreads();
  const int xcd = s_claim[0];
  const int slot = s_claim[1];
  if (slot >= 16) return;  // overprovisioned block: not needed on this XCD

  const int mt = xcd >> 1, dir = xcd & 1, jt = slot;
  const int m0 = mt * 128, j0 = jt * 32;
  const int wbase = dir * 1536;
  const int w = t >> 6, l = t & 63, lr = l & 15, lg = l >> 4;
  u32* flags = (u32*)bar + xcd * 16;  // 16 words per XCD group, AGENT-scope (L3)

  // stage w_hh bf16 slice into LDS: [kcg=kc*4+lg][col=g*32+jj][8]
  for (int c = t; c < 6144; c += 512) {
    const int col = c % 96, kcg = c / 96;
    const int g = col >> 5, jj = col & 31;
    const int k = (kcg >> 2) * 32 + (kcg & 3) * 8;
    const size_t off = (size_t)(wbase + g * 512 + j0 + jj) * 512 + k;
    *(uint4*)&wlds[c * 8] = *(const uint4*)(whh16 + off);
  }

  int jg[2];
  jg[0] = j0 + lr;
  jg[1] = j0 + 16 + lr;
  float bR[2], bZ[2], bN[2];
#pragma unroll
  for (int jn = 0; jn < 2; ++jn) {
    bR[jn] = bias_hh[wbase + jg[jn]];
    bZ[jn] = bias_hh[wbase + 512 + jg[jn]];
    bN[jn] = bias_hh[wbase + 1024 + jg[jn]];
  }
  u64 mk[4];
  int mrow[4];
  float hprev[2][4], ym[2][4];
#pragma unroll
  for (int r = 0; r < 4; ++r) {
    mrow[r] = m0 + w * 16 + lg * 4 + r;
    mk[r] = mask[mrow[r]];
#pragma unroll
    for (int jn = 0; jn < 2; ++jn) {
      hprev[jn][r] = 0.0f;
      ym[jn][r] = -3.402823466e38f;
    }
  }
  __syncthreads();  // weights staged

  const size_t arow = (size_t)(w * 16 + lr) * 512 + lg * 8;  // local A row base (u32)
  const u32* fp = &flags[l & 15];                            // lane polls one flag

  for (int s = 0; s < T_SEQ; ++s) {
    const int tok = dir ? (T_SEQ - 1 - s) : s;

    // gi prefetch (HBM/L3) BEFORE the wait: latency hides under the poll
    u16 gr[2][4], gz[2][4], gn[2][4];
#pragma unroll
    for (int jn = 0; jn < 2; ++jn)
#pragma unroll
      for (int r = 0; r < 4; ++r) {
        const size_t gb = ((size_t)mrow[r] * T_SEQ + tok) * NCOL + wbase + jg[jn];
        gr[jn][r] = __builtin_nontemporal_load(gi + gb);
        gz[jn][r] = __builtin_nontemporal_load(gi + gb + 512);
        gn[jn][r] = __builtin_nontemporal_load(gi + gb + 1024);
      }

    f32x4 acc[3][2];
#pragma unroll
    for (int g = 0; g < 3; ++g) acc[g][0] = acc[g][1] = (f32x4)0.0f;

    if (s > 0) {
      // wait for all 16 blocks' h_s with a clock-sustaining burn between polls
      {
        const u32 tgt = (u32)s;
        float ba = 1.0000001f;
        const float bm = 1.0000002f;
        while (true) {
          u32 f = __hip_atomic_load(fp, __ATOMIC_RELAXED, __HIP_MEMORY_SCOPE_AGENT);
          if (__all(f >= tgt)) break;
#pragma unroll
          for (int b = 0; b < 24; ++b)
            asm volatile("v_fmac_f32 %0, %1, %1" : "+v"(ba) : "v"(bm));
        }
        asm volatile("" ::"v"(ba));  // keep burn live
      }

      const u32* hs = hpk + ((size_t)((s & 7) * 2 + dir) * 4 + mt) * 65536;
      const u32* ap = hs + arow;
      uint4 c0 = *(const uint4*)(ap);
      uint4 c1 = *(const uint4*)(ap + 4);
#pragma unroll
      for (int kc = 0; kc < 16; ++kc) {
        uint4 n0 = c0, n1 = c1;
        if (kc < 15) {  // 2-deep software pipeline of the L2 h loads
          n0 = *(const uint4*)(ap + (kc + 1) * 32);
          n1 = *(const uint4*)(ap + (kc + 1) * 32 + 4);
        }
        u32 hw[8];
        *(uint4*)&hw[0] = c0;
        *(uint4*)&hw[4] = c1;
        u32 ahw[4], alw[4];
#pragma unroll
        for (int i = 0; i < 4; ++i) {
          ahw[i] = (hw[2 * i] & 0xFFFFu) | (hw[2 * i + 1] << 16);
          alw[i] = (hw[2 * i] >> 16) | (hw[2 * i + 1] & 0xFFFF0000u);
        }
        const s16x8 ah = __builtin_bit_cast(s16x8, *(uint4*)ahw);
        const s16x8 al = __builtin_bit_cast(s16x8, *(uint4*)alw);
        const int bb = (kc * 4 + lg) * 96;
#pragma unroll
        for (int g = 0; g < 3; ++g)
#pragma unroll
          for (int jn = 0; jn < 2; ++jn) {
            const s16x8 bh = *(const s16x8*)&wlds[(bb + g * 32 + jn * 16 + lr) * 8];
            acc[g][jn] = __builtin_amdgcn_mfma_f32_16x16x32_bf16(ah, bh, acc[g][jn], 0, 0, 0);
            acc[g][jn] = __builtin_amdgcn_mfma_f32_16x16x32_bf16(al, bh, acc[g][jn], 0, 0, 0);
          }
        c0 = n0;
        c1 = n1;
      }
    }

    // gates + h_new; store h, publish, THEN bookkeeping (off the critical path)
    float hn_v[2][4];
#pragma unroll
    for (int jn = 0; jn < 2; ++jn)
#pragma unroll
      for (int r = 0; r < 4; ++r) {
        const float rg = sigm(bf2f(gr[jn][r]) + acc[0][jn][r] + bR[jn]);
        const float zg = sigm(bf2f(gz[jn][r]) + acc[1][jn][r] + bZ[jn]);
        const float ng = fast_tanh(bf2f(gn[jn][r]) + rg * (acc[2][jn][r] + bN[jn]));
        hn_v[jn][r] = (1.0f - zg) * ng + zg * hprev[jn][r];
      }

    if (s < T_SEQ - 1) {
      u32* hd = hpk + ((size_t)(((s + 1) & 7) * 2 + dir) * 4 + mt) * 65536;
#pragma unroll
      for (int jn = 0; jn < 2; ++jn)
#pragma unroll
        for (int r = 0; r < 4; ++r) {
          const float hn = hn_v[jn][r];
          const u16 hh = f2bf(hn);
          const u16 hl = f2bf(hn - bf2f(hh));
          hd[(size_t)(w * 16 + lg * 4 + r) * 512 + jg[jn]] = (u32)hh | ((u32)hl << 16);
        }
      asm volatile("s_waitcnt vmcnt(0)" ::: "memory");  // own h stores at L2
      if (l == 0) {
        int old = atomicAdd(&s_arrive, 1);
        if (old == 8 * (s + 1) - 1)  // last wave of block: publish h_{s+1} (AGENT/L3)
          __hip_atomic_store(&flags[slot], (u32)(s + 1), __ATOMIC_RELAXED,
                             __HIP_MEMORY_SCOPE_AGENT);
      }
    }

#pragma unroll
    for (int jn = 0; jn < 2; ++jn)
#pragma unroll
      for (int r = 0; r < 4; ++r) {
        if ((mk[r] >> tok) & 1ull) ym[jn][r] = fmaxf(ym[jn][r], hn_v[jn][r]);
        hprev[jn][r] = hn_v[jn][r];
      }
  }

#pragma unroll
  for (int jn = 0; jn < 2; ++jn)
#pragma unroll
    for (int r = 0; r < 4; ++r)
      ymax[(size_t)mrow[r] * 1024 + dir * 512 + jg[jn]] = ym[jn][r];
}

extern "C" void kernel_launch(void* const* d_in, const int* in_sizes, int n_in,
                              void* d_out, int out_size, void* d_ws, size_t ws_size,
                              hipStream_t stream) {
  const int* idxs = (const int*)d_in[0];
  const float* emb = (const float*)d_in[1];
  const float* wihf = (const float*)d_in[2];
  const float* whhf = (const float*)d_in[3];
  const float* bihf = (const float*)d_in[4];
  const float* bhhf = (const float*)d_in[5];
  const float* wihb = (const float*)d_in[6];
  const float* whhb = (const float*)d_in[7];
  const float* bihb = (const float*)d_in[8];
  const float* bhhb = (const float*)d_in[9];
  float* ymax = (float*)d_out;  // [512][1024] f32

  char* ws = (char*)d_ws;
  u16* whh16 = (u16*)(ws + 0);              //  3,145,728  bf16 [3072][512]
  u16* wih = (u16*)(ws + 6291456);          //  1,966,080
  float* bias_ih = (float*)(ws + 8257536);  //     12,288
  float* bias_hh = (float*)(ws + 8269824);  //     12,288
  u64* mask = (u64*)(ws + 8282112);         //      4,096
  int* bar = (int*)(ws + 8286208);          //      4,096 (flags[0..127], claim 256..263)
  // SHARED region: emb16 (32,000,000; live only through k_gi_gemm) overlaps
  // hpk (16,777,216; [slot=8][dir=2][mt=4][128][512] u32, live only in k_gru_persist)
  u16* emb16 = (u16*)(ws + 8290304);
  u32* hpk = (u32*)(ws + 8290304);
  u16* gi = (u16*)(ws + 40290304);  // 125,829,120  bf16 [20480][3072]; ends 166,119,424
  const int use_emb16 = (ws_size >= 166119424ull) ? 1 : 0;

  k_init<<<2, 256, 0, stream>>>(idxs, mask, bar);
  if (use_emb16) k_prep_emb<<<4096, 256, 0, stream>>>(emb, emb16);
  k_prep_wih<<<3072, 320, 0, stream>>>(wihf, wihb, wih);
  k_prep_whh<<<3072, 512, 0, stream>>>(whhf, whhb, whh16);
  k_prep_bias<<<3, 1024, 0, stream>>>(bihf, bihb, bhhf, bhhb, bias_ih, bias_hh);
  k_gi_gemm<<<dim3(160, 24), 256, 0, stream>>>(idxs, emb, emb16, use_emb16, wih, bias_ih, gi);

  hipFuncSetAttribute((const void*)k_gru_persist,
                      hipFuncAttributeMaxDynamicSharedMemorySize, 98304);
  k_gru_persist<<<dim3(256), dim3(512), 98304, stream>>>(whh16, bias_hh, gi, mask, hpk,
                                                         ymax, bar);
}

// Round 11
// 862.635 us; speedup vs baseline: 1.3655x; 1.3655x over previous
//
#include <hip/hip_runtime.h>

typedef unsigned short u16;
typedef unsigned int u32;
typedef unsigned long long u64;
typedef short s16x8 __attribute__((ext_vector_type(8)));
typedef float f32x4 __attribute__((ext_vector_type(4)));
typedef u32 u32x4 __attribute__((ext_vector_type(4)));

#define T_SEQ 40
#define EMB 300
#define KPAD 320
#define NCOL 3072  // 3H * 2 dirs

__device__ __forceinline__ u16 f2bf(float x) {
  u32 u = __builtin_bit_cast(u32, x);
  u32 r = (u + 0x7fffu + ((u >> 16) & 1u)) >> 16;  // RNE
  return (u16)r;
}
__device__ __forceinline__ float bf2f(u16 h) {
  return __builtin_bit_cast(float, ((u32)h) << 16);
}
#define LOG2E 1.4426950408889634f
__device__ __forceinline__ float sigm(float x) {
  return 1.0f / (1.0f + __builtin_amdgcn_exp2f(-x * LOG2E));
}
__device__ __forceinline__ float fast_tanh(float x) {
  return 1.0f - 2.0f / (1.0f + __builtin_amdgcn_exp2f(2.0f * LOG2E * x));
}

// ---- emb f32 [V][300] -> bf16 [V][320] (zero-padded), done once
__global__ void k_prep_emb(const float* __restrict__ emb, u16* __restrict__ emb16) {
  for (int idx = blockIdx.x * 256 + threadIdx.x; idx < 50000 * 160; idx += 4096 * 256) {
    int row = idx / 160, c2 = idx - row * 160;
    int c0 = 2 * c2;
    float v0 = (c0 < EMB) ? emb[(size_t)row * EMB + c0] : 0.0f;
    float v1 = (c0 + 1 < EMB) ? emb[(size_t)row * EMB + c0 + 1] : 0.0f;
    ((u32*)emb16)[(size_t)row * 160 + c2] = (u32)f2bf(v0) | ((u32)f2bf(v1) << 16);
  }
}

// ---- pack w_ih (both dirs) to bf16, K padded 300 -> 320
__global__ void k_prep_wih(const float* __restrict__ wf, const float* __restrict__ wb,
                           u16* __restrict__ wih) {
  int n = blockIdx.x, e = threadIdx.x;
  int dir = (n >= 1536);
  int g = n - dir * 1536;
  const float* src = dir ? wb : wf;
  float v = (e < EMB) ? src[(size_t)g * EMB + e] : 0.0f;
  wih[(size_t)n * KPAD + e] = f2bf(v);
}

// ---- w_hh (both dirs) -> single bf16 (RNE)
__global__ void k_prep_whh(const float* __restrict__ wf, const float* __restrict__ wb,
                           u16* __restrict__ w16) {
  int n = blockIdx.x, k = threadIdx.x;
  int dir = (n >= 1536);
  int g = n - dir * 1536;
  float v = (dir ? wb : wf)[(size_t)g * 512 + k];
  w16[(size_t)n * 512 + k] = f2bf(v);
}

__global__ void k_prep_bias(const float* __restrict__ bihf, const float* __restrict__ bihb,
                            const float* __restrict__ bhhf, const float* __restrict__ bhhb,
                            float* __restrict__ bias_ih, float* __restrict__ bias_hh) {
  int i = blockIdx.x * 1024 + threadIdx.x;
  if (i >= 3072) return;
  int dir = (i >= 1536);
  int g = i - dir * 1536;
  bias_ih[i] = dir ? bihb[g] : bihf[g];
  bias_hh[i] = dir ? bhhb[g] : bhhf[g];
}

// ---- phase A: gi[tok][n] = emb16[idx[tok]] . wih[n] + b_ih[n], output bf16 (nt stores).
__global__ __launch_bounds__(256) void k_gi_gemm(
    const int* __restrict__ idxs, const float* __restrict__ emb,
    const u16* __restrict__ emb16, int use_emb16,
    const u16* __restrict__ wih, const float* __restrict__ bias_ih,
    u16* __restrict__ gi) {
  __shared__ __align__(16) char smem[34816];
  u16(*As)[40] = (u16(*)[40])smem;            // 10240 B
  u16(*Bs)[40] = (u16(*)[40])(smem + 10240);  // 10240 B
  u16(*Cs)[136] = (u16(*)[136])smem;          // 34816 B (reused after K loop)

  const int m0 = blockIdx.x * 128;
  const int n0 = blockIdx.y * 128;
  const int t = threadIdx.x;
  const int w = t >> 6, l = t & 63;
  const int wm = (w >> 1) * 64, wn = (w & 1) * 64;
  const int lr = l & 15, lg = l >> 4;

  f32x4 acc[4][4];
#pragma unroll
  for (int i = 0; i < 4; ++i)
#pragma unroll
    for (int j = 0; j < 4; ++j) acc[i][j] = (f32x4)0.0f;

  const int arow = t >> 1, aseg = t & 1;
  const int tok = idxs[m0 + arow];
  const float* aerow = emb + (size_t)tok * EMB;
  const u16* aerow16 = emb16 + (size_t)tok * KPAD;
  const u16* brow_p = wih + (size_t)(n0 + arow) * KPAD;

  for (int kc = 0; kc < 10; ++kc) {
    const int k0 = kc * 32;
    if (use_emb16) {
      *(uint4*)&As[arow][aseg * 16] = *(const uint4*)(aerow16 + k0 + aseg * 16);
      *(uint4*)(&As[arow][aseg * 16] + 8) = *(const uint4*)(aerow16 + k0 + aseg * 16 + 8);
    } else {
      int cb = k0 + aseg * 16;
      u16* d = &As[arow][aseg * 16];
      if (cb + 15 < EMB) {
        const float4* s = (const float4*)(aerow + cb);
        float4 v0 = s[0], v1 = s[1], v2 = s[2], v3 = s[3];
        uint4 w0, w1;
        w0.x = (u32)f2bf(v0.x) | ((u32)f2bf(v0.y) << 16);
        w0.y = (u32)f2bf(v0.z) | ((u32)f2bf(v0.w) << 16);
        w0.z = (u32)f2bf(v1.x) | ((u32)f2bf(v1.y) << 16);
        w0.w = (u32)f2bf(v1.z) | ((u32)f2bf(v1.w) << 16);
        w1.x = (u32)f2bf(v2.x) | ((u32)f2bf(v2.y) << 16);
        w1.y = (u32)f2bf(v2.z) | ((u32)f2bf(v2.w) << 16);
        w1.z = (u32)f2bf(v3.x) | ((u32)f2bf(v3.y) << 16);
        w1.w = (u32)f2bf(v3.z) | ((u32)f2bf(v3.w) << 16);
        *(uint4*)d = w0;
        *(uint4*)(d + 8) = w1;
      } else {
#pragma unroll
        for (int e = 0; e < 16; ++e) {
          int c = cb + e;
          d[e] = (c < EMB) ? f2bf(aerow[c]) : (u16)0;
        }
      }
    }
    {
      const u16* s = brow_p + k0 + aseg * 16;
      u16* d = &Bs[arow][aseg * 16];
      *(uint4*)d = *(const uint4*)s;
      *(uint4*)(d + 8) = *(const uint4*)(s + 8);
    }
    __syncthreads();
    s16x8 av[4], bv[4];
#pragma unroll
    for (int i = 0; i < 4; ++i) av[i] = *(const s16x8*)&As[wm + i * 16 + lr][lg * 8];
#pragma unroll
    for (int j = 0; j < 4; ++j) bv[j] = *(const s16x8*)&Bs[wn + j * 16 + lr][lg * 8];
#pragma unroll
    for (int i = 0; i < 4; ++i)
#pragma unroll
      for (int j = 0; j < 4; ++j)
        acc[i][j] = __builtin_amdgcn_mfma_f32_16x16x32_bf16(av[i], bv[j], acc[i][j], 0, 0, 0);
    __syncthreads();
  }

  float bj[4];
#pragma unroll
  for (int j = 0; j < 4; ++j) bj[j] = bias_ih[n0 + wn + j * 16 + lr];
#pragma unroll
  for (int i = 0; i < 4; ++i)
#pragma unroll
    for (int j = 0; j < 4; ++j)
#pragma unroll
      for (int r = 0; r < 4; ++r)
        Cs[wm + i * 16 + lg * 4 + r][wn + j * 16 + lr] = f2bf(acc[i][j][r] + bj[j]);
  __syncthreads();
#pragma unroll
  for (int rr = t >> 4; rr < 128; rr += 16) {
    const int cseg = (t & 15) * 8;
    __builtin_nontemporal_store(*(const u32x4*)&Cs[rr][cseg],
                                (u32x4*)(gi + (size_t)(m0 + rr) * NCOL + n0 + cseg));
  }
}

// ---- phase B: one GRU step (both dirs), 40 sequential launches (kernel boundary =
// the barrier; no flags, no spinning). Block = (m-tile 64, j-tile 32, dir), 512 thr
// = 8 waves (4 m-quarters x 2 j-halves). w_hh slice (96KB bf16) staged to LDS with
// row-contiguous (fully coalesced) global reads into the R8 fragment layout
// ([kseg][col][8], measured 0 bank conflicts). h: packed u32 hi|lo, ping-pong slots.
// gi bf16 nontemporal. ymax: s=0 plain write (replay-safe), s>0 masked fmax RMW.
__global__ __launch_bounds__(512) void k_step(
    const u16* __restrict__ whh16, const float* __restrict__ bias_hh,
    const u16* __restrict__ gi, const int* __restrict__ idxs,
    u32* __restrict__ hpk, float* __restrict__ ymax, int s) {
  extern __shared__ u16 blds[];  // [64 kseg][96 col][8] u16 = 96 KB
  const int m0 = blockIdx.x * 64, j0 = blockIdx.y * 32;
  const int dir = blockIdx.z;
  const int wbase = dir * 1536;
  const int t = threadIdx.x, w = t >> 6, l = t & 63, lr = l & 15, lg = l >> 4;
  const int mq = w >> 1, jh = w & 1;
  const int tok = dir ? (T_SEQ - 1 - s) : s;

  const u32* hs = hpk + (size_t)((s & 1) * 2 + dir) * 262144;
  u32* hd = hpk + (size_t)(((s + 1) & 1) * 2 + dir) * 262144;

  // stage w slice: thread block reads 96 rows x 1KB, row-contiguous (coalesced)
  if (s > 0) {
    for (int c = t; c < 6144; c += 512) {
      const int rr = c >> 6, kseg = c & 63;  // row rr, 16B-chunk kseg
      const int g = rr >> 5, jj = rr & 31;
      *(uint4*)&blds[((size_t)kseg * 96 + g * 32 + jj) * 8] =
          *(const uint4*)(whh16 + (size_t)(wbase + g * 512 + j0 + jj) * 512 + kseg * 8);
    }
  }

  const int jg = j0 + jh * 16 + lr;
  int mrow[4], msk[4];
  u16 gr[4], gz[4], gn[4];
  float hp[4];
#pragma unroll
  for (int r = 0; r < 4; ++r) {
    mrow[r] = m0 + mq * 16 + lg * 4 + r;
    const size_t gb = ((size_t)mrow[r] * T_SEQ + tok) * NCOL + wbase + jg;
    gr[r] = __builtin_nontemporal_load(gi + gb);
    gz[r] = __builtin_nontemporal_load(gi + gb + 512);
    gn[r] = __builtin_nontemporal_load(gi + gb + 1024);
    msk[r] = idxs[mrow[r] * T_SEQ + tok];
    if (s > 0) {
      const u32 v = hs[(size_t)mrow[r] * 512 + jg];
      hp[r] = bf2f((u16)(v & 0xFFFFu)) + bf2f((u16)(v >> 16));
    } else {
      hp[r] = 0.0f;
    }
  }
  const float bR = bias_hh[wbase + jg];
  const float bZ = bias_hh[wbase + 512 + jg];
  const float bN = bias_hh[wbase + 1024 + jg];

  f32x4 acc[3];
  acc[0] = acc[1] = acc[2] = (f32x4)0.0f;

  if (s > 0) {
    __syncthreads();  // w slice staged
    const u32* ap = hs + (size_t)(m0 + mq * 16 + lr) * 512 + lg * 8;
    uint4 c0 = *(const uint4*)ap;
    uint4 c1 = *(const uint4*)(ap + 4);
#pragma unroll
    for (int kc = 0; kc < 16; ++kc) {
      uint4 n0 = c0, n1 = c1;
      if (kc < 15) {  // 2-deep pipeline of the h loads
        n0 = *(const uint4*)(ap + (kc + 1) * 32);
        n1 = *(const uint4*)(ap + (kc + 1) * 32 + 4);
      }
      u32 hw[8];
      *(uint4*)&hw[0] = c0;
      *(uint4*)&hw[4] = c1;
      u32 ahw[4], alw[4];
#pragma unroll
      for (int i = 0; i < 4; ++i) {
        ahw[i] = (hw[2 * i] & 0xFFFFu) | (hw[2 * i + 1] << 16);
        alw[i] = (hw[2 * i] >> 16) | (hw[2 * i + 1] & 0xFFFF0000u);
      }
      const s16x8 ah = __builtin_bit_cast(s16x8, *(uint4*)ahw);
      const s16x8 al = __builtin_bit_cast(s16x8, *(uint4*)alw);
      const int bb = ((kc * 4 + lg) * 96 + jh * 16 + lr) * 8;
#pragma unroll
      for (int g = 0; g < 3; ++g) {
        const s16x8 bh = *(const s16x8*)&blds[bb + g * 256];
        acc[g] = __builtin_amdgcn_mfma_f32_16x16x32_bf16(ah, bh, acc[g], 0, 0, 0);
        acc[g] = __builtin_amdgcn_mfma_f32_16x16x32_bf16(al, bh, acc[g], 0, 0, 0);
      }
      c0 = n0;
      c1 = n1;
    }
  }

#pragma unroll
  for (int r = 0; r < 4; ++r) {
    const float rg = sigm(bf2f(gr[r]) + acc[0][r] + bR);
    const float zg = sigm(bf2f(gz[r]) + acc[1][r] + bZ);
    const float ng = fast_tanh(bf2f(gn[r]) + rg * (acc[2][r] + bN));
    const float hn = (1.0f - zg) * ng + zg * hp[r];
    if (s < T_SEQ - 1) {
      const u16 hh = f2bf(hn);
      const u16 hl = f2bf(hn - bf2f(hh));
      hd[(size_t)mrow[r] * 512 + jg] = (u32)hh | ((u32)hl << 16);
    }
    float* yp = ymax + (size_t)mrow[r] * 1024 + dir * 512 + jg;
    if (s == 0) {
      *yp = msk[r] ? hn : -3.402823466e38f;  // init (replay-safe: unconditional write)
    } else if (msk[r]) {
      *yp = fmaxf(*yp, hn);
    }
  }
}

extern "C" void kernel_launch(void* const* d_in, const int* in_sizes, int n_in,
                              void* d_out, int out_size, void* d_ws, size_t ws_size,
                              hipStream_t stream) {
  const int* idxs = (const int*)d_in[0];
  const float* emb = (const float*)d_in[1];
  const float* wihf = (const float*)d_in[2];
  const float* whhf = (const float*)d_in[3];
  const float* bihf = (const float*)d_in[4];
  const float* bhhf = (const float*)d_in[5];
  const float* wihb = (const float*)d_in[6];
  const float* whhb = (const float*)d_in[7];
  const float* bihb = (const float*)d_in[8];
  const float* bhhb = (const float*)d_in[9];
  float* ymax = (float*)d_out;  // [512][1024] f32

  char* ws = (char*)d_ws;
  u16* whh16 = (u16*)(ws + 0);              //  3,145,728  bf16 [3072][512]
  u16* wih = (u16*)(ws + 6291456);          //  1,966,080
  float* bias_ih = (float*)(ws + 8257536);  //     12,288
  float* bias_hh = (float*)(ws + 8269824);  //     12,288
  // SHARED region: emb16 (32,000,000; live only through k_gi_gemm) overlaps
  // hpk (4,194,304; [slot=2][dir=2][512][512] u32, live only in k_step)
  u16* emb16 = (u16*)(ws + 8290304);
  u32* hpk = (u32*)(ws + 8290304);
  u16* gi = (u16*)(ws + 40290304);  // 125,829,120  bf16 [20480][3072]; ends 166,119,424
  const int use_emb16 = (ws_size >= 166119424ull) ? 1 : 0;

  if (use_emb16) k_prep_emb<<<4096, 256, 0, stream>>>(emb, emb16);
  k_prep_wih<<<3072, 320, 0, stream>>>(wihf, wihb, wih);
  k_prep_whh<<<3072, 512, 0, stream>>>(whhf, whhb, whh16);
  k_prep_bias<<<3, 1024, 0, stream>>>(bihf, bihb, bhhf, bhhb, bias_ih, bias_hh);
  k_gi_gemm<<<dim3(160, 24), 256, 0, stream>>>(idxs, emb, emb16, use_emb16, wih, bias_ih, gi);

  hipFuncSetAttribute((const void*)k_step, hipFuncAttributeMaxDynamicSharedMemorySize,
                      98304);
  for (int s = 0; s < T_SEQ; ++s)
    k_step<<<dim3(8, 16, 2), 512, 98304, stream>>>(whh16, bias_hh, gi, idxs, hpk, ymax, s);
}

// Round 12
// 861.132 us; speedup vs baseline: 1.3679x; 1.0017x over previous
//
#include <hip/hip_runtime.h>

typedef unsigned short u16;
typedef unsigned int u32;
typedef unsigned long long u64;
typedef short s16x8 __attribute__((ext_vector_type(8)));
typedef float f32x4 __attribute__((ext_vector_type(4)));

#define T_SEQ 40
#define EMB 300
#define KPAD 320
#define NCOL 3072  // 3H * 2 dirs

__device__ __forceinline__ u16 f2bf(float x) {
  u32 u = __builtin_bit_cast(u32, x);
  u32 r = (u + 0x7fffu + ((u >> 16) & 1u)) >> 16;  // RNE
  return (u16)r;
}
__device__ __forceinline__ float bf2f(u16 h) {
  return __builtin_bit_cast(float, ((u32)h) << 16);
}
#define LOG2E 1.4426950408889634f
__device__ __forceinline__ float sigm(float x) {
  return 1.0f / (1.0f + __builtin_amdgcn_exp2f(-x * LOG2E));
}
__device__ __forceinline__ float fast_tanh(float x) {
  return 1.0f - 2.0f / (1.0f + __builtin_amdgcn_exp2f(2.0f * LOG2E * x));
}

// ---- emb f32 [V][300] -> bf16 [V][320] (zero-padded), done once
__global__ void k_prep_emb(const float* __restrict__ emb, u16* __restrict__ emb16) {
  for (int idx = blockIdx.x * 256 + threadIdx.x; idx < 50000 * 160; idx += 4096 * 256) {
    int row = idx / 160, c2 = idx - row * 160;
    int c0 = 2 * c2;
    float v0 = (c0 < EMB) ? emb[(size_t)row * EMB + c0] : 0.0f;
    float v1 = (c0 + 1 < EMB) ? emb[(size_t)row * EMB + c0 + 1] : 0.0f;
    ((u32*)emb16)[(size_t)row * 160 + c2] = (u32)f2bf(v0) | ((u32)f2bf(v1) << 16);
  }
}

// ---- pack w_ih (both dirs) to bf16, K padded 300 -> 320
__global__ void k_prep_wih(const float* __restrict__ wf, const float* __restrict__ wb,
                           u16* __restrict__ wih) {
  int n = blockIdx.x, e = threadIdx.x;
  int dir = (n >= 1536);
  int g = n - dir * 1536;
  const float* src = dir ? wb : wf;
  float v = (e < EMB) ? src[(size_t)g * EMB + e] : 0.0f;
  wih[(size_t)n * KPAD + e] = f2bf(v);
}

// ---- w_hh (both dirs) -> single bf16 (RNE)
__global__ void k_prep_whh(const float* __restrict__ wf, const float* __restrict__ wb,
                           u16* __restrict__ w16) {
  int n = blockIdx.x, k = threadIdx.x;
  int dir = (n >= 1536);
  int g = n - dir * 1536;
  float v = (dir ? wb : wf)[(size_t)g * 512 + k];
  w16[(size_t)n * 512 + k] = f2bf(v);
}

__global__ void k_prep_bias(const float* __restrict__ bihf, const float* __restrict__ bihb,
                            const float* __restrict__ bhhf, const float* __restrict__ bhhb,
                            float* __restrict__ bias_ih, float* __restrict__ bias_hh) {
  int i = blockIdx.x * 1024 + threadIdx.x;
  if (i >= 3072) return;
  int dir = (i >= 1536);
  int g = i - dir * 1536;
  bias_ih[i] = dir ? bihb[g] : bihf[g];
  bias_hh[i] = dir ? bhhb[g] : bhhf[g];
}

// ---- phase A: gi[tok][n] = emb16[idx[tok]] . wih[n] + b_ih[n], output bf16.
// PLAIN stores: gi (126 MB) stays in L2/L3 (fits in 256 MB Infinity Cache) so the
// 40 step kernels read it as L3 hits instead of HBM.
__global__ __launch_bounds__(256) void k_gi_gemm(
    const int* __restrict__ idxs, const float* __restrict__ emb,
    const u16* __restrict__ emb16, int use_emb16,
    const u16* __restrict__ wih, const float* __restrict__ bias_ih,
    u16* __restrict__ gi) {
  __shared__ __align__(16) char smem[34816];
  u16(*As)[40] = (u16(*)[40])smem;            // 10240 B
  u16(*Bs)[40] = (u16(*)[40])(smem + 10240);  // 10240 B
  u16(*Cs)[136] = (u16(*)[136])smem;          // 34816 B (reused after K loop)

  const int m0 = blockIdx.x * 128;
  const int n0 = blockIdx.y * 128;
  const int t = threadIdx.x;
  const int w = t >> 6, l = t & 63;
  const int wm = (w >> 1) * 64, wn = (w & 1) * 64;
  const int lr = l & 15, lg = l >> 4;

  f32x4 acc[4][4];
#pragma unroll
  for (int i = 0; i < 4; ++i)
#pragma unroll
    for (int j = 0; j < 4; ++j) acc[i][j] = (f32x4)0.0f;

  const int arow = t >> 1, aseg = t & 1;
  const int tok = idxs[m0 + arow];
  const float* aerow = emb + (size_t)tok * EMB;
  const u16* aerow16 = emb16 + (size_t)tok * KPAD;
  const u16* brow_p = wih + (size_t)(n0 + arow) * KPAD;

  for (int kc = 0; kc < 10; ++kc) {
    const int k0 = kc * 32;
    if (use_emb16) {
      *(uint4*)&As[arow][aseg * 16] = *(const uint4*)(aerow16 + k0 + aseg * 16);
      *(uint4*)(&As[arow][aseg * 16] + 8) = *(const uint4*)(aerow16 + k0 + aseg * 16 + 8);
    } else {
      int cb = k0 + aseg * 16;
      u16* d = &As[arow][aseg * 16];
      if (cb + 15 < EMB) {
        const float4* s = (const float4*)(aerow + cb);
        float4 v0 = s[0], v1 = s[1], v2 = s[2], v3 = s[3];
        uint4 w0, w1;
        w0.x = (u32)f2bf(v0.x) | ((u32)f2bf(v0.y) << 16);
        w0.y = (u32)f2bf(v0.z) | ((u32)f2bf(v0.w) << 16);
        w0.z = (u32)f2bf(v1.x) | ((u32)f2bf(v1.y) << 16);
        w0.w = (u32)f2bf(v1.z) | ((u32)f2bf(v1.w) << 16);
        w1.x = (u32)f2bf(v2.x) | ((u32)f2bf(v2.y) << 16);
        w1.y = (u32)f2bf(v2.z) | ((u32)f2bf(v2.w) << 16);
        w1.z = (u32)f2bf(v3.x) | ((u32)f2bf(v3.y) << 16);
        w1.w = (u32)f2bf(v3.z) | ((u32)f2bf(v3.w) << 16);
        *(uint4*)d = w0;
        *(uint4*)(d + 8) = w1;
      } else {
#pragma unroll
        for (int e = 0; e < 16; ++e) {
          int c = cb + e;
          d[e] = (c < EMB) ? f2bf(aerow[c]) : (u16)0;
        }
      }
    }
    {
      const u16* s = brow_p + k0 + aseg * 16;
      u16* d = &Bs[arow][aseg * 16];
      *(uint4*)d = *(const uint4*)s;
      *(uint4*)(d + 8) = *(const uint4*)(s + 8);
    }
    __syncthreads();
    s16x8 av[4], bv[4];
#pragma unroll
    for (int i = 0; i < 4; ++i) av[i] = *(const s16x8*)&As[wm + i * 16 + lr][lg * 8];
#pragma unroll
    for (int j = 0; j < 4; ++j) bv[j] = *(const s16x8*)&Bs[wn + j * 16 + lr][lg * 8];
#pragma unroll
    for (int i = 0; i < 4; ++i)
#pragma unroll
      for (int j = 0; j < 4; ++j)
        acc[i][j] = __builtin_amdgcn_mfma_f32_16x16x32_bf16(av[i], bv[j], acc[i][j], 0, 0, 0);
    __syncthreads();
  }

  float bj[4];
#pragma unroll
  for (int j = 0; j < 4; ++j) bj[j] = bias_ih[n0 + wn + j * 16 + lr];
#pragma unroll
  for (int i = 0; i < 4; ++i)
#pragma unroll
    for (int j = 0; j < 4; ++j)
#pragma unroll
      for (int r = 0; r < 4; ++r)
        Cs[wm + i * 16 + lg * 4 + r][wn + j * 16 + lr] = f2bf(acc[i][j][r] + bj[j]);
  __syncthreads();
#pragma unroll
  for (int rr = t >> 4; rr < 128; rr += 16) {
    const int cseg = (t & 15) * 8;
    *(uint4*)(gi + (size_t)(m0 + rr) * NCOL + n0 + cseg) = *(const uint4*)&Cs[rr][cseg];
  }
}

// ---- phase B: one GRU step (both dirs), 40 sequential launches (kernel boundary =
// the barrier). Block = (m-tile 64, j-tile 32, dir), 512 thr = 8 waves (4 mq x 2 jh).
// KEY (R12): ALL 16 h A-fragments (32 uint4/thread) loaded up front before W staging
// -> one L3 latency exposure instead of 16 serialized ones; K-loop is pure LDS+MFMA.
// gi plain loads (L3-resident). __launch_bounds__(512,2) keeps VGPR<=256 (2 w/SIMD).
__global__ __launch_bounds__(512, 2) void k_step(
    const u16* __restrict__ whh16, const float* __restrict__ bias_hh,
    const u16* __restrict__ gi, const int* __restrict__ idxs,
    u32* __restrict__ hpk, float* __restrict__ ymax, int s) {
  extern __shared__ u16 blds[];  // [64 kseg][96 col][8] u16 = 96 KB
  const int m0 = blockIdx.x * 64, j0 = blockIdx.y * 32;
  const int dir = blockIdx.z;
  const int wbase = dir * 1536;
  const int t = threadIdx.x, w = t >> 6, l = t & 63, lr = l & 15, lg = l >> 4;
  const int mq = w >> 1, jh = w & 1;
  const int tok = dir ? (T_SEQ - 1 - s) : s;

  const u32* hs = hpk + (size_t)((s & 1) * 2 + dir) * 262144;
  u32* hd = hpk + (size_t)(((s + 1) & 1) * 2 + dir) * 262144;
  const int jg = j0 + jh * 16 + lr;

  // (1) issue ALL h A-fragment loads (independent of LDS; one latency exposure)
  uint4 hq0[16], hq1[16];
  if (s > 0) {
    const u32* ap = hs + (size_t)(m0 + mq * 16 + lr) * 512 + lg * 8;
#pragma unroll
    for (int kc = 0; kc < 16; ++kc) {
      hq0[kc] = *(const uint4*)(ap + kc * 32);
      hq1[kc] = *(const uint4*)(ap + kc * 32 + 4);
    }
  }

  // (2) issue gi + h_prev + mask loads (needed only in the epilogue)
  int mrow[4], msk[4];
  u16 gr[4], gz[4], gn[4];
  float hp[4];
#pragma unroll
  for (int r = 0; r < 4; ++r) {
    mrow[r] = m0 + mq * 16 + lg * 4 + r;
    const size_t gb = ((size_t)mrow[r] * T_SEQ + tok) * NCOL + wbase + jg;
    gr[r] = gi[gb];
    gz[r] = gi[gb + 512];
    gn[r] = gi[gb + 1024];
    msk[r] = idxs[mrow[r] * T_SEQ + tok];
    if (s > 0) {
      const u32 v = hs[(size_t)mrow[r] * 512 + jg];
      hp[r] = bf2f((u16)(v & 0xFFFFu)) + bf2f((u16)(v >> 16));
    } else {
      hp[r] = 0.0f;
    }
  }
  const float bR = bias_hh[wbase + jg];
  const float bZ = bias_hh[wbase + 512 + jg];
  const float bN = bias_hh[wbase + 1024 + jg];

  // (3) stage W slice to LDS (row-contiguous coalesced reads; overlaps (1)/(2))
  if (s > 0) {
    for (int c = t; c < 6144; c += 512) {
      const int rr = c >> 6, kseg = c & 63;
      const int g = rr >> 5, jj = rr & 31;
      *(uint4*)&blds[((size_t)kseg * 96 + g * 32 + jj) * 8] =
          *(const uint4*)(whh16 + (size_t)(wbase + g * 512 + j0 + jj) * 512 + kseg * 8);
    }
  }

  f32x4 acc[3];
  acc[0] = acc[1] = acc[2] = (f32x4)0.0f;

  if (s > 0) {
    __syncthreads();  // W staged; h already in registers
#pragma unroll
    for (int kc = 0; kc < 16; ++kc) {
      u32 hw[8];
      *(uint4*)&hw[0] = hq0[kc];
      *(uint4*)&hw[4] = hq1[kc];
      u32 ahw[4], alw[4];
#pragma unroll
      for (int i = 0; i < 4; ++i) {
        ahw[i] = (hw[2 * i] & 0xFFFFu) | (hw[2 * i + 1] << 16);
        alw[i] = (hw[2 * i] >> 16) | (hw[2 * i + 1] & 0xFFFF0000u);
      }
      const s16x8 ah = __builtin_bit_cast(s16x8, *(uint4*)ahw);
      const s16x8 al = __builtin_bit_cast(s16x8, *(uint4*)alw);
      const int bb = ((kc * 4 + lg) * 96 + jh * 16 + lr) * 8;
#pragma unroll
      for (int g = 0; g < 3; ++g) {
        const s16x8 bh = *(const s16x8*)&blds[bb + g * 256];
        acc[g] = __builtin_amdgcn_mfma_f32_16x16x32_bf16(ah, bh, acc[g], 0, 0, 0);
        acc[g] = __builtin_amdgcn_mfma_f32_16x16x32_bf16(al, bh, acc[g], 0, 0, 0);
      }
    }
  }

#pragma unroll
  for (int r = 0; r < 4; ++r) {
    const float rg = sigm(bf2f(gr[r]) + acc[0][r] + bR);
    const float zg = sigm(bf2f(gz[r]) + acc[1][r] + bZ);
    const float ng = fast_tanh(bf2f(gn[r]) + rg * (acc[2][r] + bN));
    const float hn = (1.0f - zg) * ng + zg * hp[r];
    if (s < T_SEQ - 1) {
      const u16 hh = f2bf(hn);
      const u16 hl = f2bf(hn - bf2f(hh));
      hd[(size_t)mrow[r] * 512 + jg] = (u32)hh | ((u32)hl << 16);
    }
    float* yp = ymax + (size_t)mrow[r] * 1024 + dir * 512 + jg;
    if (s == 0) {
      *yp = msk[r] ? hn : -3.402823466e38f;  // init (replay-safe: unconditional write)
    } else if (msk[r]) {
      *yp = fmaxf(*yp, hn);
    }
  }
}

extern "C" void kernel_launch(void* const* d_in, const int* in_sizes, int n_in,
                              void* d_out, int out_size, void* d_ws, size_t ws_size,
                              hipStream_t stream) {
  const int* idxs = (const int*)d_in[0];
  const float* emb = (const float*)d_in[1];
  const float* wihf = (const float*)d_in[2];
  const float* whhf = (const float*)d_in[3];
  const float* bihf = (const float*)d_in[4];
  const float* bhhf = (const float*)d_in[5];
  const float* wihb = (const float*)d_in[6];
  const float* whhb = (const float*)d_in[7];
  const float* bihb = (const float*)d_in[8];
  const float* bhhb = (const float*)d_in[9];
  float* ymax = (float*)d_out;  // [512][1024] f32

  char* ws = (char*)d_ws;
  u16* whh16 = (u16*)(ws + 0);              //  3,145,728  bf16 [3072][512]
  u16* wih = (u16*)(ws + 6291456);          //  1,966,080
  float* bias_ih = (float*)(ws + 8257536);  //     12,288
  float* bias_hh = (float*)(ws + 8269824);  //     12,288
  // SHARED region: emb16 (32,000,000; live only through k_gi_gemm) overlaps
  // hpk (4,194,304; [slot=2][dir=2][512][512] u32, live only in k_step)
  u16* emb16 = (u16*)(ws + 8290304);
  u32* hpk = (u32*)(ws + 8290304);
  u16* gi = (u16*)(ws + 40290304);  // 125,829,120  bf16 [20480][3072]; ends 166,119,424
  const int use_emb16 = (ws_size >= 166119424ull) ? 1 : 0;

  if (use_emb16) k_prep_emb<<<4096, 256, 0, stream>>>(emb, emb16);
  k_prep_wih<<<3072, 320, 0, stream>>>(wihf, wihb, wih);
  k_prep_whh<<<3072, 512, 0, stream>>>(whhf, whhb, whh16);
  k_prep_bias<<<3, 1024, 0, stream>>>(bihf, bihb, bhhf, bhhb, bias_ih, bias_hh);
  k_gi_gemm<<<dim3(160, 24), 256, 0, stream>>>(idxs, emb, emb16, use_emb16, wih, bias_ih, gi);

  hipFuncSetAttribute((const void*)k_step, hipFuncAttributeMaxDynamicSharedMemorySize,
                      98304);
  for (int s = 0; s < T_SEQ; ++s)
    k_step<<<dim3(8, 16, 2), 512, 98304, stream>>>(whh16, bias_hh, gi, idxs, hpk, ymax, s);
}